// Round 1
// baseline (281.296 us; speedup 1.0000x reference)
//
#include <hip/hip_runtime.h>

// VQ embedding, bf16-MFMA, register-pipelined B + packed uint argmin.
// z: (B=64, D=256, H=32, W=32) fp32; codebook: (K=1024, D=256) fp32.
// argmin_k ||z_n - c_k||^2 = argmin_k (1 + ||c_k||^2 - 2 z.c_k)   [shift keeps score > 0]
// Packed key: (float_bits(score) & 0xFFFFFC00) | k  -> uint min = argmin w/ first-index ties.
// Outputs (flat fp32): st[16777216] = chosen codebook row, indices[65536] as float,
// loss = 1.25 * (sum z^2 + sum (best_score - 1)).
//
// R1: 64-row tiles (32 KB LDS) -> 4 blocks/CU, 16 waves/CU (~50% occupancy, was 22%).
// 4 waves share all 64 rows, split 1024 codes 4-way (64 codes/wave per 256-code kt sweep).
// Inner loop identical to the 128-row version (same MFMA/load mix, same swizzle).

#define IDX_OFF  16777216
#define LOSS_OFF 16842752

typedef __bf16 bf16x8 __attribute__((ext_vector_type(8)));
typedef float  f32x4  __attribute__((ext_vector_type(4)));

// ---------------- Kernel 1: cb fp32 -> bf16 copy + (1 + row norm) ----------------
__global__ __launch_bounds__(256) void vq_prep(const float* __restrict__ cb,
                                               __bf16* __restrict__ cbh,
                                               float* __restrict__ sc1) {
    const int t = threadIdx.x;
    const int r = blockIdx.x * 16 + (t >> 4);
    const int d0 = (t & 15) * 16;
    const float* src = cb + (size_t)r * 256 + d0;
    __bf16* dst = cbh + (size_t)r * 256 + d0;
    float s = 0.f;
    float4 f[4];
    #pragma unroll
    for (int p = 0; p < 4; p++) f[p] = *(const float4*)(src + p * 4);
    bf16x8 v0, v1;
    #pragma unroll
    for (int p = 0; p < 4; p++) {
        s = fmaf(f[p].x, f[p].x, s); s = fmaf(f[p].y, f[p].y, s);
        s = fmaf(f[p].z, f[p].z, s); s = fmaf(f[p].w, f[p].w, s);
    }
    v0[0]=(__bf16)f[0].x; v0[1]=(__bf16)f[0].y; v0[2]=(__bf16)f[0].z; v0[3]=(__bf16)f[0].w;
    v0[4]=(__bf16)f[1].x; v0[5]=(__bf16)f[1].y; v0[6]=(__bf16)f[1].z; v0[7]=(__bf16)f[1].w;
    v1[0]=(__bf16)f[2].x; v1[1]=(__bf16)f[2].y; v1[2]=(__bf16)f[2].z; v1[3]=(__bf16)f[2].w;
    v1[4]=(__bf16)f[3].x; v1[5]=(__bf16)f[3].y; v1[6]=(__bf16)f[3].z; v1[7]=(__bf16)f[3].w;
    *(bf16x8*)dst = v0;
    *(bf16x8*)(dst + 8) = v1;
    s += __shfl_xor(s, 1, 64);
    s += __shfl_xor(s, 2, 64);
    s += __shfl_xor(s, 4, 64);
    s += __shfl_xor(s, 8, 64);
    if ((t & 15) == 0) sc1[r] = s + 1.0f;
}

// ---------------- Kernel 2: MFMA distance-GEMM + argmin + outputs ----------------
// Block: 64 n-rows x all 1024 codes. 4 waves: each wave covers all 64 rows (4 row-frags)
// and 64 codes per 256-code kt chunk (codes kt + w*64 + j*16 + m16). LDS 32 KB z tile
// [64][256] bf16, XOR-swizzled; recycled as argmin scratch, then as chosen-q tile for
// coalesced emit. No barriers in K-loop; B-frags register-double-buffered from
// L2-resident bf16 codebook. 1024 blocks = exactly 4 per CU.
__global__ __launch_bounds__(256, 4) void vq_mfma(const float* __restrict__ z,
                                                  const __bf16* __restrict__ cbh,
                                                  const float* __restrict__ sc1,
                                                  float* __restrict__ out) {
    __shared__ __align__(16) __bf16 z_s[64 * 256];    // 32768 B
    __shared__ float red_s[4];

    const int t    = threadIdx.x;
    const int lane = t & 63;
    const int w    = t >> 6;
    const int m16  = lane & 15;
    const int q4   = lane >> 4;
    const int blk  = blockIdx.x;
    const int b    = blk >> 4;
    const int hw0  = (blk & 15) << 6;
    const int n0   = blk << 6;

    // B double-buffer: preload kt=0 frags immediately (in flight during phase A)
    bf16x8 bb[4];
    {
        const __bf16* bp = cbh + (size_t)(w * 64 + m16) * 256 + q4 * 8;
        #pragma unroll
        for (int j = 0; j < 4; j++) bb[j] = *(const bf16x8*)(bp + (size_t)j * 4096);
    }

    // ---- phase A: stage z (fp32 global, coalesced) -> bf16 LDS [n][d]; sum z^2
    float lz = 0.f;
    {
        const int nl   = t & 63;          // row (hw)
        const int dseg = t >> 6;          // d segment: dseg*64 .. dseg*64+63
        const float* zp = z + (size_t)(b * 256 + dseg * 64) * 1024 + hw0 + nl;
        #pragma unroll
        for (int p = 0; p < 8; p++) {
            bf16x8 v;
            #pragma unroll
            for (int j = 0; j < 8; j++) {
                float f = zp[(size_t)(p * 8 + j) * 1024];
                lz = fmaf(f, f, lz);
                v[j] = (__bf16)f;
            }
            int gs = (dseg * 8 + p) ^ (nl & 7);
            *(bf16x8*)&z_s[nl * 256 + gs * 8] = v;
        }
    }
    __syncthreads();

    // ---- GEMM + packed-uint running argmin (no barriers, pipelined B)
    unsigned int best[16];
    #pragma unroll
    for (int i = 0; i < 16; i++) best[i] = 0xFFFFFFFFu;

    #pragma unroll 1
    for (int kt = 0; kt < 1024; kt += 256) {
        // per-kt code norms (+1) and packed indices — loads hidden under MFMAs
        int   kcv[4];
        float sck[4];
        #pragma unroll
        for (int j = 0; j < 4; j++) {
            kcv[j] = kt + w * 64 + j * 16 + m16;
            sck[j] = sc1[kcv[j]];
        }
        const __bf16* bc  = cbh + (size_t)(kt + w * 64 + m16) * 256 + q4 * 8;
        const int ktn = (kt + 256) & 1023;
        const __bf16* bnx = cbh + (size_t)(ktn + w * 64 + m16) * 256 + q4 * 8;

        f32x4 acc[4][4];
        #pragma unroll
        for (int i = 0; i < 4; i++)
            #pragma unroll
            for (int j = 0; j < 4; j++) acc[i][j] = (f32x4){0.f, 0.f, 0.f, 0.f};

        #pragma unroll
        for (int dc = 0; dc < 256; dc += 32) {
            // prefetch next chunk's B (next kt's dc=0 on the last chunk)
            bf16x8 bn[4];
            const __bf16* bp = (dc == 224) ? bnx : (bc + dc + 32);
            #pragma unroll
            for (int j = 0; j < 4; j++) bn[j] = *(const bf16x8*)(bp + (size_t)j * 4096);

            bf16x8 a[4];
            const int gs = ((dc >> 3) + q4) ^ (m16 & 7);
            #pragma unroll
            for (int i = 0; i < 4; i++)
                a[i] = *(const bf16x8*)&z_s[(i * 16 + m16) * 256 + gs * 8];

            #pragma unroll
            for (int i = 0; i < 4; i++)
                #pragma unroll
                for (int j = 0; j < 4; j++)
                    acc[i][j] = __builtin_amdgcn_mfma_f32_16x16x32_bf16(a[i], bb[j], acc[i][j], 0, 0, 0);

            #pragma unroll
            for (int j = 0; j < 4; j++) bb[j] = bn[j];
        }

        // packed argmin: score = 1 + ||c||^2 - 2 z.c  > 0 always
        #pragma unroll
        for (int j = 0; j < 4; j++) {
            #pragma unroll
            for (int i = 0; i < 4; i++)
                #pragma unroll
                for (int r = 0; r < 4; r++) {
                    float v3 = fmaf(-2.f, acc[i][j][r], sck[j]);
                    unsigned int key = (__float_as_uint(v3) & 0xFFFFFC00u) | (unsigned int)kcv[j];
                    int pos = i * 4 + r;
                    best[pos] = min(best[pos], key);
                }
        }
    }

    // ---- intra-wave min across the 16 col-lanes
    #pragma unroll
    for (int pos = 0; pos < 16; pos++) {
        unsigned int k = best[pos];
        #pragma unroll
        for (int off = 1; off < 16; off <<= 1)
            k = min(k, (unsigned int)__shfl_xor((int)k, off, 64));
        best[pos] = k;
    }
    __syncthreads();              // all z_s reads done -> z_s becomes scratch

    // ---- cross-wave combine in recycled z_s
    unsigned int* ks = (unsigned int*)z_s;   // ks[0..256): key[wave][row]; ks[256..320): chosen k
    if (m16 == 0) {
        #pragma unroll
        for (int pos = 0; pos < 16; pos++) {
            int i = pos >> 2, r = pos & 3;
            int row = i * 16 + q4 * 4 + r;
            ks[w * 64 + row] = best[pos];
        }
    }
    __syncthreads();
    if (t < 64) {
        unsigned int key = min(min(ks[t], ks[64 + t]), min(ks[128 + t], ks[192 + t]));
        int kf = (int)(key & 1023u);
        ks[256 + t] = (unsigned int)kf;
        out[IDX_OFF + n0 + t] = (float)kf;
        lz += __uint_as_float(key & 0xFFFFFC00u) - 1.0f;   // best score (unshifted)
    }
    {
        float s = lz;
        #pragma unroll
        for (int off = 1; off < 64; off <<= 1) s += __shfl_xor(s, off, 64);
        if (lane == 0) red_s[w] = s;
    }
    __syncthreads();              // ks[256..320) and red_s visible
    if (t == 0)
        atomicAdd(out + LOSS_OFF, 1.25f * ((red_s[0] + red_s[1]) + (red_s[2] + red_s[3])));

    // ---- stage chosen codebook rows into z_s, then coalesced emit
    const int qrow = t >> 2;              // 0..63
    const int qoff = (t & 3) * 64;        // d offset 0/64/128/192
    const int myk  = (int)ks[256 + qrow];
    __syncthreads();              // everyone read their k; safe to overwrite z_s
    {
        const __bf16* qp = cbh + (size_t)myk * 256 + qoff;
        #pragma unroll
        for (int p = 0; p < 8; p++) {
            bf16x8 v = *(const bf16x8*)(qp + p * 8);
            int gs = ((qoff >> 3) + p) ^ (qrow & 7);
            *(bf16x8*)&z_s[qrow * 256 + gs * 8] = v;
        }
    }
    __syncthreads();
    {
        const int nl   = t & 63;
        const int dseg = t >> 6;
        float* op = out + (size_t)(b * 256 + dseg * 64) * 1024 + hw0 + nl;
        #pragma unroll
        for (int p = 0; p < 8; p++) {
            int gs = (dseg * 8 + p) ^ (nl & 7);
            bf16x8 v = *(const bf16x8*)&z_s[nl * 256 + gs * 8];
            #pragma unroll
            for (int j = 0; j < 8; j++)
                op[(size_t)(p * 8 + j) * 1024] = (float)v[j];
        }
    }
}

extern "C" void kernel_launch(void* const* d_in, const int* in_sizes, int n_in,
                              void* d_out, int out_size, void* d_ws, size_t ws_size,
                              hipStream_t stream) {
    const float* z  = (const float*)d_in[0];   // 16777216
    const float* cb = (const float*)d_in[1];   // 262144
    float* out = (float*)d_out;

    float*  sc1 = (float*)d_ws;                        // 1024 f  (1 + ||c||^2)
    __bf16* cbh = (__bf16*)((char*)d_ws + 8192);       // 512 KB bf16 codebook

    hipMemsetAsync(out + LOSS_OFF, 0, sizeof(float), stream);   // capture-safe
    vq_prep<<<64, 256, 0, stream>>>(cb, cbh, sc1);
    vq_mfma<<<1024, 256, 0, stream>>>(z, cbh, sc1, out);
}

// Round 2
// 257.951 us; speedup vs baseline: 1.0905x; 1.0905x over previous
//
#include <hip/hip_runtime.h>

// VQ embedding, bf16-MFMA, register-pipelined B + packed uint argmin.
// z: (B=64, D=256, H=32, W=32) fp32; codebook: (K=1024, D=256) fp32.
// argmin_k ||z_n - c_k||^2 = argmin_k (1 + ||c_k||^2 - 2 z.c_k)   [shift keeps score > 0]
// Packed key: (float_bits(score) & 0xFFFFFC00) | k  -> uint min = argmin w/ first-index ties.
// Outputs (flat fp32): st[16777216] = chosen codebook row, indices[65536] as float,
// loss = 1.25 * (sum z^2 + sum (best_score - 1)).
//
// R2: 64-row tile (32 KB LDS) at 4 blocks/CU, with acc[2][4] (32 regs) so the whole
// wave state fits the 128-reg/wave budget of __launch_bounds__(256,4) WITHOUT spilling
// (R1 spilled: VGPR=64 + 470 MB scratch traffic). Waves: rows (w>>1)*32, codes
// (w&1)*64 of each 128-code kt chunk; 8 kt chunks.

#define IDX_OFF  16777216
#define LOSS_OFF 16842752

typedef __bf16 bf16x8 __attribute__((ext_vector_type(8)));
typedef float  f32x4  __attribute__((ext_vector_type(4)));

// ---------------- Kernel 1: cb fp32 -> bf16 copy + (1 + row norm) ----------------
__global__ __launch_bounds__(256) void vq_prep(const float* __restrict__ cb,
                                               __bf16* __restrict__ cbh,
                                               float* __restrict__ sc1) {
    const int t = threadIdx.x;
    const int r = blockIdx.x * 16 + (t >> 4);
    const int d0 = (t & 15) * 16;
    const float* src = cb + (size_t)r * 256 + d0;
    __bf16* dst = cbh + (size_t)r * 256 + d0;
    float s = 0.f;
    float4 f[4];
    #pragma unroll
    for (int p = 0; p < 4; p++) f[p] = *(const float4*)(src + p * 4);
    bf16x8 v0, v1;
    #pragma unroll
    for (int p = 0; p < 4; p++) {
        s = fmaf(f[p].x, f[p].x, s); s = fmaf(f[p].y, f[p].y, s);
        s = fmaf(f[p].z, f[p].z, s); s = fmaf(f[p].w, f[p].w, s);
    }
    v0[0]=(__bf16)f[0].x; v0[1]=(__bf16)f[0].y; v0[2]=(__bf16)f[0].z; v0[3]=(__bf16)f[0].w;
    v0[4]=(__bf16)f[1].x; v0[5]=(__bf16)f[1].y; v0[6]=(__bf16)f[1].z; v0[7]=(__bf16)f[1].w;
    v1[0]=(__bf16)f[2].x; v1[1]=(__bf16)f[2].y; v1[2]=(__bf16)f[2].z; v1[3]=(__bf16)f[2].w;
    v1[4]=(__bf16)f[3].x; v1[5]=(__bf16)f[3].y; v1[6]=(__bf16)f[3].z; v1[7]=(__bf16)f[3].w;
    *(bf16x8*)dst = v0;
    *(bf16x8*)(dst + 8) = v1;
    s += __shfl_xor(s, 1, 64);
    s += __shfl_xor(s, 2, 64);
    s += __shfl_xor(s, 4, 64);
    s += __shfl_xor(s, 8, 64);
    if ((t & 15) == 0) sc1[r] = s + 1.0f;
}

// ---------------- Kernel 2: MFMA distance-GEMM + argmin + outputs ----------------
// Block: 64 n-rows x all 1024 codes. 4 waves: wn=(w>>1)*32 rows (2 frags),
// wk=(w&1)*64 codes (4 frags) of each 128-wide kt chunk. LDS 32 KB z tile [64][256]
// bf16, XOR-swizzled; recycled as argmin scratch, then as chosen-q tile for coalesced
// emit. No barriers in K-loop; B-frags register-double-buffered from L2-resident
// bf16 codebook. 1024 blocks = exactly 4 per CU.
__global__ __launch_bounds__(256, 4) void vq_mfma(const float* __restrict__ z,
                                                  const __bf16* __restrict__ cbh,
                                                  const float* __restrict__ sc1,
                                                  float* __restrict__ out) {
    __shared__ __align__(16) __bf16 z_s[64 * 256];    // 32768 B
    __shared__ float red_s[4];

    const int t    = threadIdx.x;
    const int lane = t & 63;
    const int w    = t >> 6;
    const int m16  = lane & 15;
    const int q4   = lane >> 4;
    const int wn   = (w >> 1) * 32;
    const int wk   = (w & 1) * 64;
    const int blk  = blockIdx.x;
    const int b    = blk >> 4;
    const int hw0  = (blk & 15) << 6;
    const int n0   = blk << 6;

    // B double-buffer: preload kt=0 frags immediately (in flight during phase A)
    bf16x8 bb[4];
    {
        const __bf16* bp = cbh + (size_t)(wk + m16) * 256 + q4 * 8;
        #pragma unroll
        for (int j = 0; j < 4; j++) bb[j] = *(const bf16x8*)(bp + (size_t)j * 4096);
    }

    // ---- phase A: stage z (fp32 global, coalesced) -> bf16 LDS [n][d]; sum z^2
    float lz = 0.f;
    {
        const int nl   = t & 63;          // row (hw)
        const int dseg = t >> 6;          // d segment: dseg*64 .. dseg*64+63
        const float* zp = z + (size_t)(b * 256 + dseg * 64) * 1024 + hw0 + nl;
        #pragma unroll
        for (int p = 0; p < 8; p++) {
            bf16x8 v;
            #pragma unroll
            for (int j = 0; j < 8; j++) {
                float f = zp[(size_t)(p * 8 + j) * 1024];
                lz = fmaf(f, f, lz);
                v[j] = (__bf16)f;
            }
            int gs = (dseg * 8 + p) ^ (nl & 7);
            *(bf16x8*)&z_s[nl * 256 + gs * 8] = v;
        }
    }
    __syncthreads();

    // ---- GEMM + packed-uint running argmin (no barriers, pipelined B)
    unsigned int best[8];
    #pragma unroll
    for (int i = 0; i < 8; i++) best[i] = 0xFFFFFFFFu;

    const int arow = wn + m16;
    #pragma unroll 1
    for (int kt = 0; kt < 1024; kt += 128) {
        // per-kt code norms (+1) and packed indices — loads hidden under MFMAs
        int   kcv[4];
        float sck[4];
        #pragma unroll
        for (int j = 0; j < 4; j++) {
            kcv[j] = kt + wk + j * 16 + m16;
            sck[j] = sc1[kcv[j]];
        }
        const __bf16* bc  = cbh + (size_t)(kt + wk + m16) * 256 + q4 * 8;
        const int ktn = (kt + 128) & 1023;
        const __bf16* bnx = cbh + (size_t)(ktn + wk + m16) * 256 + q4 * 8;

        f32x4 acc[2][4];
        #pragma unroll
        for (int i = 0; i < 2; i++)
            #pragma unroll
            for (int j = 0; j < 4; j++) acc[i][j] = (f32x4){0.f, 0.f, 0.f, 0.f};

        #pragma unroll
        for (int dc = 0; dc < 256; dc += 32) {
            // prefetch next chunk's B (next kt's dc=0 on the last chunk)
            bf16x8 bn[4];
            const __bf16* bp = (dc == 224) ? bnx : (bc + dc + 32);
            #pragma unroll
            for (int j = 0; j < 4; j++) bn[j] = *(const bf16x8*)(bp + (size_t)j * 4096);

            bf16x8 a[2];
            const int gs = ((dc >> 3) + q4) ^ (m16 & 7);
            #pragma unroll
            for (int i = 0; i < 2; i++)
                a[i] = *(const bf16x8*)&z_s[(arow + i * 16) * 256 + gs * 8];

            #pragma unroll
            for (int i = 0; i < 2; i++)
                #pragma unroll
                for (int j = 0; j < 4; j++)
                    acc[i][j] = __builtin_amdgcn_mfma_f32_16x16x32_bf16(a[i], bb[j], acc[i][j], 0, 0, 0);

            #pragma unroll
            for (int j = 0; j < 4; j++) bb[j] = bn[j];
        }

        // packed argmin: score = 1 + ||c||^2 - 2 z.c  > 0 always
        #pragma unroll
        for (int j = 0; j < 4; j++) {
            #pragma unroll
            for (int i = 0; i < 2; i++)
                #pragma unroll
                for (int r = 0; r < 4; r++) {
                    float v3 = fmaf(-2.f, acc[i][j][r], sck[j]);
                    unsigned int key = (__float_as_uint(v3) & 0xFFFFFC00u) | (unsigned int)kcv[j];
                    int pos = i * 4 + r;
                    best[pos] = min(best[pos], key);
                }
        }
    }

    // ---- intra-wave min across the 16 col-lanes
    #pragma unroll
    for (int pos = 0; pos < 8; pos++) {
        unsigned int k = best[pos];
        #pragma unroll
        for (int off = 1; off < 16; off <<= 1)
            k = min(k, (unsigned int)__shfl_xor((int)k, off, 64));
        best[pos] = k;
    }
    __syncthreads();              // all z_s reads done -> z_s becomes scratch

    // ---- cross-wave combine in recycled z_s
    // ks[0..128): key[codehalf(w&1)][row]; ks[256..320): chosen k
    unsigned int* ks = (unsigned int*)z_s;
    if (m16 == 0) {
        #pragma unroll
        for (int pos = 0; pos < 8; pos++) {
            int i = pos >> 2, r = pos & 3;
            int row = wn + i * 16 + q4 * 4 + r;
            ks[(w & 1) * 64 + row] = best[pos];
        }
    }
    __syncthreads();
    if (t < 64) {
        unsigned int key = min(ks[t], ks[64 + t]);
        int kf = (int)(key & 1023u);
        ks[256 + t] = (unsigned int)kf;
        out[IDX_OFF + n0 + t] = (float)kf;
        lz += __uint_as_float(key & 0xFFFFFC00u) - 1.0f;   // best score (unshifted)
    }
    {
        float s = lz;
        #pragma unroll
        for (int off = 1; off < 64; off <<= 1) s += __shfl_xor(s, off, 64);
        if (lane == 0) red_s[w] = s;
    }
    __syncthreads();              // ks[256..320) and red_s visible
    if (t == 0)
        atomicAdd(out + LOSS_OFF, 1.25f * ((red_s[0] + red_s[1]) + (red_s[2] + red_s[3])));

    // ---- stage chosen codebook rows into z_s, then coalesced emit
    const int qrow = t >> 2;              // 0..63
    const int qoff = (t & 3) * 64;        // d offset 0/64/128/192
    const int myk  = (int)ks[256 + qrow];
    __syncthreads();              // everyone read their k; safe to overwrite z_s
    {
        const __bf16* qp = cbh + (size_t)myk * 256 + qoff;
        #pragma unroll
        for (int p = 0; p < 8; p++) {
            bf16x8 v = *(const bf16x8*)(qp + p * 8);
            int gs = ((qoff >> 3) + p) ^ (qrow & 7);
            *(bf16x8*)&z_s[qrow * 256 + gs * 8] = v;
        }
    }
    __syncthreads();
    {
        const int nl   = t & 63;
        const int dseg = t >> 6;
        float* op = out + (size_t)(b * 256 + dseg * 64) * 1024 + hw0 + nl;
        #pragma unroll
        for (int p = 0; p < 8; p++) {
            int gs = (dseg * 8 + p) ^ (nl & 7);
            bf16x8 v = *(const bf16x8*)&z_s[nl * 256 + gs * 8];
            #pragma unroll
            for (int j = 0; j < 8; j++)
                op[(size_t)(p * 8 + j) * 1024] = (float)v[j];
        }
    }
}

extern "C" void kernel_launch(void* const* d_in, const int* in_sizes, int n_in,
                              void* d_out, int out_size, void* d_ws, size_t ws_size,
                              hipStream_t stream) {
    const float* z  = (const float*)d_in[0];   // 16777216
    const float* cb = (const float*)d_in[1];   // 262144
    float* out = (float*)d_out;

    float*  sc1 = (float*)d_ws;                        // 1024 f  (1 + ||c||^2)
    __bf16* cbh = (__bf16*)((char*)d_ws + 8192);       // 512 KB bf16 codebook

    hipMemsetAsync(out + LOSS_OFF, 0, sizeof(float), stream);   // capture-safe
    vq_prep<<<64, 256, 0, stream>>>(cb, cbh, sc1);
    vq_mfma<<<1024, 256, 0, stream>>>(z, cbh, sc1, out);
}

// Round 3
// 181.651 us; speedup vs baseline: 1.5486x; 1.4200x over previous
//
#include <hip/hip_runtime.h>

// VQ embedding, bf16-MFMA, register-pipelined B + packed uint argmin.
// z: (B=64, D=256, H=32, W=32) fp32; codebook: (K=1024, D=256) fp32.
// argmin_k ||z_n - c_k||^2 = argmin_k (1 + ||c_k||^2 - 2 z.c_k)   [shift keeps score > 0]
// Packed key: (float_bits(score) & 0xFFFFFC00) | k  -> uint min = argmin w/ first-index ties.
// Outputs (flat fp32): st[16777216] = chosen codebook row, indices[65536] as float,
// loss = 1.25 * (sum z^2 + sum (best_score - 1)).
//
// R3: 64-row tile (32 KB LDS, 4 blocks/CU) with rows x1 / codes x4 wave split:
// each wave computes ALL 64 rows (a[4], acc[4][2]) against its own 32-code quarter
// of each 128-code chunk -> NO B duplication (block B-traffic = 1x codebook, total
// equal to R0) at 2x R0's wave count, and R0's 8-MFMA:2-load ratio. Blocks start
// the code sweep at rotated kt0=(blk&3)*256 to desync the 4 resident blocks' L2
// streams. Registers ~110 unified < 128 -> 16 waves/CU under (256,2) budget.

#define IDX_OFF  16777216
#define LOSS_OFF 16842752

typedef __bf16 bf16x8 __attribute__((ext_vector_type(8)));
typedef float  f32x4  __attribute__((ext_vector_type(4)));

// ---------------- Kernel 1: cb fp32 -> bf16 copy + (1 + row norm) ----------------
__global__ __launch_bounds__(256) void vq_prep(const float* __restrict__ cb,
                                               __bf16* __restrict__ cbh,
                                               float* __restrict__ sc1) {
    const int t = threadIdx.x;
    const int r = blockIdx.x * 16 + (t >> 4);
    const int d0 = (t & 15) * 16;
    const float* src = cb + (size_t)r * 256 + d0;
    __bf16* dst = cbh + (size_t)r * 256 + d0;
    float s = 0.f;
    float4 f[4];
    #pragma unroll
    for (int p = 0; p < 4; p++) f[p] = *(const float4*)(src + p * 4);
    bf16x8 v0, v1;
    #pragma unroll
    for (int p = 0; p < 4; p++) {
        s = fmaf(f[p].x, f[p].x, s); s = fmaf(f[p].y, f[p].y, s);
        s = fmaf(f[p].z, f[p].z, s); s = fmaf(f[p].w, f[p].w, s);
    }
    v0[0]=(__bf16)f[0].x; v0[1]=(__bf16)f[0].y; v0[2]=(__bf16)f[0].z; v0[3]=(__bf16)f[0].w;
    v0[4]=(__bf16)f[1].x; v0[5]=(__bf16)f[1].y; v0[6]=(__bf16)f[1].z; v0[7]=(__bf16)f[1].w;
    v1[0]=(__bf16)f[2].x; v1[1]=(__bf16)f[2].y; v1[2]=(__bf16)f[2].z; v1[3]=(__bf16)f[2].w;
    v1[4]=(__bf16)f[3].x; v1[5]=(__bf16)f[3].y; v1[6]=(__bf16)f[3].z; v1[7]=(__bf16)f[3].w;
    *(bf16x8*)dst = v0;
    *(bf16x8*)(dst + 8) = v1;
    s += __shfl_xor(s, 1, 64);
    s += __shfl_xor(s, 2, 64);
    s += __shfl_xor(s, 4, 64);
    s += __shfl_xor(s, 8, 64);
    if ((t & 15) == 0) sc1[r] = s + 1.0f;
}

// ---------------- Kernel 2: MFMA distance-GEMM + argmin + outputs ----------------
// Block: 64 n-rows x all 1024 codes. 4 waves: each wave all 64 rows (4 row-frags)
// x its own 32 codes (2 frags) of each 128-code chunk. LDS 32 KB z tile [64][256]
// bf16, XOR-swizzled; recycled as argmin scratch, then as chosen-q tile for
// coalesced emit. No barriers in K-loop; B-frags register-double-buffered from
// L2-resident bf16 codebook. 1024 blocks = 4 per CU, kt-rotated per block.
__global__ __launch_bounds__(256, 2) void vq_mfma(const float* __restrict__ z,
                                                  const __bf16* __restrict__ cbh,
                                                  const float* __restrict__ sc1,
                                                  float* __restrict__ out) {
    __shared__ __align__(16) __bf16 z_s[64 * 256];    // 32768 B
    __shared__ float red_s[4];

    const int t    = threadIdx.x;
    const int lane = t & 63;
    const int w    = t >> 6;
    const int m16  = lane & 15;
    const int q4   = lane >> 4;
    const int wc   = w << 5;              // wave's code offset within a 128-chunk
    const int blk  = blockIdx.x;
    const int b    = blk >> 4;
    const int hw0  = (blk & 15) << 6;
    const int n0   = blk << 6;
    const int kt0  = (blk & 3) << 8;      // rotated code-sweep start (desync L2 streams)

    // B double-buffer: preload first chunk's frags immediately (in flight during phase A)
    bf16x8 bb[2];
    {
        const __bf16* bp = cbh + (size_t)(kt0 + wc + m16) * 256 + q4 * 8;
        bb[0] = *(const bf16x8*)bp;
        bb[1] = *(const bf16x8*)(bp + 4096);
    }

    // ---- phase A: stage z (fp32 global, coalesced) -> bf16 LDS [n][d]; sum z^2
    float lz = 0.f;
    {
        const int nl   = t & 63;          // row (hw)
        const int dseg = t >> 6;          // d segment: dseg*64 .. dseg*64+63
        const float* zp = z + (size_t)(b * 256 + dseg * 64) * 1024 + hw0 + nl;
        #pragma unroll
        for (int p = 0; p < 8; p++) {
            bf16x8 v;
            #pragma unroll
            for (int j = 0; j < 8; j++) {
                float f = zp[(size_t)(p * 8 + j) * 1024];
                lz = fmaf(f, f, lz);
                v[j] = (__bf16)f;
            }
            int gs = (dseg * 8 + p) ^ (nl & 7);
            *(bf16x8*)&z_s[nl * 256 + gs * 8] = v;
        }
    }
    __syncthreads();

    // ---- GEMM + packed-uint running argmin (no barriers, pipelined B)
    unsigned int best[16];
    #pragma unroll
    for (int i = 0; i < 16; i++) best[i] = 0xFFFFFFFFu;

    #pragma unroll 1
    for (int it = 0; it < 8; it++) {
        const int kt  = (kt0 + (it << 7)) & 1023;
        const int ktn = (kt0 + (((it + 1) & 7) << 7)) & 1023;
        // per-chunk code norms (+1) and packed indices — loads hidden under MFMAs
        int   kcv[2];
        float sck[2];
        #pragma unroll
        for (int j = 0; j < 2; j++) {
            kcv[j] = kt + wc + j * 16 + m16;
            sck[j] = sc1[kcv[j]];
        }
        const __bf16* bc  = cbh + (size_t)(kt + wc + m16) * 256 + q4 * 8;
        const __bf16* bnx = cbh + (size_t)(ktn + wc + m16) * 256 + q4 * 8;

        f32x4 acc[4][2];
        #pragma unroll
        for (int i = 0; i < 4; i++)
            #pragma unroll
            for (int j = 0; j < 2; j++) acc[i][j] = (f32x4){0.f, 0.f, 0.f, 0.f};

        #pragma unroll
        for (int dc = 0; dc < 256; dc += 32) {
            // prefetch next chunk's B (next kt's dc=0 on the last chunk)
            bf16x8 bn[2];
            const __bf16* bp = (dc == 224) ? bnx : (bc + dc + 32);
            bn[0] = *(const bf16x8*)bp;
            bn[1] = *(const bf16x8*)(bp + 4096);

            bf16x8 a[4];
            const int gs = ((dc >> 3) + q4) ^ (m16 & 7);
            #pragma unroll
            for (int i = 0; i < 4; i++)
                a[i] = *(const bf16x8*)&z_s[(i * 16 + m16) * 256 + gs * 8];

            #pragma unroll
            for (int i = 0; i < 4; i++)
                #pragma unroll
                for (int j = 0; j < 2; j++)
                    acc[i][j] = __builtin_amdgcn_mfma_f32_16x16x32_bf16(a[i], bb[j], acc[i][j], 0, 0, 0);

            bb[0] = bn[0];
            bb[1] = bn[1];
        }

        // packed argmin: score = 1 + ||c||^2 - 2 z.c  > 0 always
        #pragma unroll
        for (int j = 0; j < 2; j++) {
            #pragma unroll
            for (int i = 0; i < 4; i++)
                #pragma unroll
                for (int r = 0; r < 4; r++) {
                    float v3 = fmaf(-2.f, acc[i][j][r], sck[j]);
                    unsigned int key = (__float_as_uint(v3) & 0xFFFFFC00u) | (unsigned int)kcv[j];
                    int pos = i * 4 + r;
                    best[pos] = min(best[pos], key);
                }
        }
    }

    // ---- intra-wave min across the 16 col-lanes
    #pragma unroll
    for (int pos = 0; pos < 16; pos++) {
        unsigned int k = best[pos];
        #pragma unroll
        for (int off = 1; off < 16; off <<= 1)
            k = min(k, (unsigned int)__shfl_xor((int)k, off, 64));
        best[pos] = k;
    }
    __syncthreads();              // all z_s reads done -> z_s becomes scratch

    // ---- cross-wave combine in recycled z_s
    // ks[0..256): key[wave][row] (each wave owns a distinct code quarter);
    // ks[256..320): chosen k
    unsigned int* ks = (unsigned int*)z_s;
    if (m16 == 0) {
        #pragma unroll
        for (int pos = 0; pos < 16; pos++) {
            int i = pos >> 2, r = pos & 3;
            int row = i * 16 + q4 * 4 + r;
            ks[w * 64 + row] = best[pos];
        }
    }
    __syncthreads();
    if (t < 64) {
        unsigned int key = min(min(ks[t], ks[64 + t]), min(ks[128 + t], ks[192 + t]));
        int kf = (int)(key & 1023u);
        ks[256 + t] = (unsigned int)kf;
        out[IDX_OFF + n0 + t] = (float)kf;
        lz += __uint_as_float(key & 0xFFFFFC00u) - 1.0f;   // best score (unshifted)
    }
    {
        float s = lz;
        #pragma unroll
        for (int off = 1; off < 64; off <<= 1) s += __shfl_xor(s, off, 64);
        if (lane == 0) red_s[w] = s;
    }
    __syncthreads();              // ks[256..320) and red_s visible
    if (t == 0)
        atomicAdd(out + LOSS_OFF, 1.25f * ((red_s[0] + red_s[1]) + (red_s[2] + red_s[3])));

    // ---- stage chosen codebook rows into z_s, then coalesced emit
    const int qrow = t >> 2;              // 0..63
    const int qoff = (t & 3) * 64;        // d offset 0/64/128/192
    const int myk  = (int)ks[256 + qrow];
    __syncthreads();              // everyone read their k; safe to overwrite z_s
    {
        const __bf16* qp = cbh + (size_t)myk * 256 + qoff;
        #pragma unroll
        for (int p = 0; p < 8; p++) {
            bf16x8 v = *(const bf16x8*)(qp + p * 8);
            int gs = ((qoff >> 3) + p) ^ (qrow & 7);
            *(bf16x8*)&z_s[qrow * 256 + gs * 8] = v;
        }
    }
    __syncthreads();
    {
        const int nl   = t & 63;
        const int dseg = t >> 6;
        float* op = out + (size_t)(b * 256 + dseg * 64) * 1024 + hw0 + nl;
        #pragma unroll
        for (int p = 0; p < 8; p++) {
            int gs = (dseg * 8 + p) ^ (nl & 7);
            bf16x8 v = *(const bf16x8*)&z_s[nl * 256 + gs * 8];
            #pragma unroll
            for (int j = 0; j < 8; j++)
                op[(size_t)(p * 8 + j) * 1024] = (float)v[j];
        }
    }
}

extern "C" void kernel_launch(void* const* d_in, const int* in_sizes, int n_in,
                              void* d_out, int out_size, void* d_ws, size_t ws_size,
                              hipStream_t stream) {
    const float* z  = (const float*)d_in[0];   // 16777216
    const float* cb = (const float*)d_in[1];   // 262144
    float* out = (float*)d_out;

    float*  sc1 = (float*)d_ws;                        // 1024 f  (1 + ||c||^2)
    __bf16* cbh = (__bf16*)((char*)d_ws + 8192);       // 512 KB bf16 codebook

    hipMemsetAsync(out + LOSS_OFF, 0, sizeof(float), stream);   // capture-safe
    vq_prep<<<64, 256, 0, stream>>>(cb, cbh, sc1);
    vq_mfma<<<1024, 256, 0, stream>>>(z, cbh, sc1, out);
}

// Round 4
// 181.240 us; speedup vs baseline: 1.5521x; 1.0023x over previous
//
#include <hip/hip_runtime.h>

// VQ embedding, bf16-MFMA, software-pipelined K-loop + packed uint argmin.
// z: (B=64, D=256, H=32, W=32) fp32; codebook: (K=1024, D=256) fp32.
// argmin_k ||z_n - c_k||^2 = argmin_k (1 + ||c_k||^2 - 2 z.c_k)   [shift keeps score > 0]
// Packed key: (float_bits(score) & 0xFFFFFC00) | k  -> uint min = argmin w/ first-index ties.
// Outputs (flat fp32): st[16777216] = chosen codebook row, indices[65536] as float,
// loss = 1.25 * (sum z^2 + sum (best_score - 1)).
//
// R4 (on R3's 64-row, codes-x4 structure): attack intra-wave latency (proven lever;
// TLP proven useless R2 vs R3):
//  - B-frags prefetched 2 dc-iterations ahead (bb0/bb1/bn rotate): ~2 iterations of
//    MFMA+issue cover the ~200-400 cyc L2 latency (was 1 iteration = exposed).
//  - A-frags (ds_read_b128) prefetched 1 iteration ahead (~120 cyc LDS latency covered).
//  - Phase A: float4 z loads along hw (16 loads/thread, was 64 scalar), in-register
//    transpose to the same swizzled ds_write_b128 pattern.
// Registers ~150 unified -> 2 waves/SIMD under (256,2); no spill.

#define IDX_OFF  16777216
#define LOSS_OFF 16842752

typedef __bf16 bf16x8 __attribute__((ext_vector_type(8)));
typedef float  f32x4  __attribute__((ext_vector_type(4)));

// ---------------- Kernel 1: cb fp32 -> bf16 copy + (1 + row norm) ----------------
__global__ __launch_bounds__(256) void vq_prep(const float* __restrict__ cb,
                                               __bf16* __restrict__ cbh,
                                               float* __restrict__ sc1) {
    const int t = threadIdx.x;
    const int r = blockIdx.x * 16 + (t >> 4);
    const int d0 = (t & 15) * 16;
    const float* src = cb + (size_t)r * 256 + d0;
    __bf16* dst = cbh + (size_t)r * 256 + d0;
    float s = 0.f;
    float4 f[4];
    #pragma unroll
    for (int p = 0; p < 4; p++) f[p] = *(const float4*)(src + p * 4);
    bf16x8 v0, v1;
    #pragma unroll
    for (int p = 0; p < 4; p++) {
        s = fmaf(f[p].x, f[p].x, s); s = fmaf(f[p].y, f[p].y, s);
        s = fmaf(f[p].z, f[p].z, s); s = fmaf(f[p].w, f[p].w, s);
    }
    v0[0]=(__bf16)f[0].x; v0[1]=(__bf16)f[0].y; v0[2]=(__bf16)f[0].z; v0[3]=(__bf16)f[0].w;
    v0[4]=(__bf16)f[1].x; v0[5]=(__bf16)f[1].y; v0[6]=(__bf16)f[1].z; v0[7]=(__bf16)f[1].w;
    v1[0]=(__bf16)f[2].x; v1[1]=(__bf16)f[2].y; v1[2]=(__bf16)f[2].z; v1[3]=(__bf16)f[2].w;
    v1[4]=(__bf16)f[3].x; v1[5]=(__bf16)f[3].y; v1[6]=(__bf16)f[3].z; v1[7]=(__bf16)f[3].w;
    *(bf16x8*)dst = v0;
    *(bf16x8*)(dst + 8) = v1;
    s += __shfl_xor(s, 1, 64);
    s += __shfl_xor(s, 2, 64);
    s += __shfl_xor(s, 4, 64);
    s += __shfl_xor(s, 8, 64);
    if ((t & 15) == 0) sc1[r] = s + 1.0f;
}

// ---------------- Kernel 2: MFMA distance-GEMM + argmin + outputs ----------------
// Block: 64 n-rows x all 1024 codes. 4 waves: each wave all 64 rows (4 row-frags)
// x its own 32 codes (2 frags) of each 128-code chunk. LDS 32 KB z tile [64][256]
// bf16, XOR-swizzled; recycled as argmin scratch, then as chosen-q tile for
// coalesced emit. No barriers in K-loop. 1024 blocks, kt-rotated per block.
__global__ __launch_bounds__(256, 2) void vq_mfma(const float* __restrict__ z,
                                                  const __bf16* __restrict__ cbh,
                                                  const float* __restrict__ sc1,
                                                  float* __restrict__ out) {
    __shared__ __align__(16) __bf16 z_s[64 * 256];    // 32768 B
    __shared__ float red_s[4];

    const int t    = threadIdx.x;
    const int lane = t & 63;
    const int w    = t >> 6;
    const int m16  = lane & 15;
    const int q4   = lane >> 4;
    const int wc   = w << 5;              // wave's code offset within a 128-chunk
    const int blk  = blockIdx.x;
    const int b    = blk >> 4;
    const int hw0  = (blk & 15) << 6;
    const int n0   = blk << 6;
    const int kt0  = (blk & 3) << 8;      // rotated code-sweep start (desync L2 streams)

    // B pipeline preload: (kt0, dc=0) and (kt0, dc=32) frag pairs, in flight during phase A
    bf16x8 bb0[2], bb1[2];
    {
        const __bf16* bp = cbh + (size_t)(kt0 + wc + m16) * 256 + q4 * 8;
        bb0[0] = *(const bf16x8*)bp;
        bb0[1] = *(const bf16x8*)(bp + 4096);
        bb1[0] = *(const bf16x8*)(bp + 32);
        bb1[1] = *(const bf16x8*)(bp + 32 + 4096);
    }

    // ---- phase A: stage z (fp32 global, float4 along hw) -> bf16 LDS [n][d]; sum z^2
    float lz = 0.f;
    {
        const int rg    = (t & 15) * 4;       // 4-row group
        const int dbase = (t >> 4) * 16;      // 16 d's per thread
        const float* zp = z + (size_t)b * 262144 + hw0 + rg;
        #pragma unroll
        for (int batch = 0; batch < 2; batch++) {
            float4 f[8];
            #pragma unroll
            for (int j = 0; j < 8; j++)
                f[j] = *(const float4*)(zp + (size_t)(dbase + batch * 8 + j) * 1024);
            const float* fp = (const float*)f;
            #pragma unroll
            for (int r = 0; r < 4; r++) {
                bf16x8 v;
                #pragma unroll
                for (int j = 0; j < 8; j++) {
                    float x = fp[j * 4 + r];
                    lz = fmaf(x, x, lz);
                    v[j] = (__bf16)x;
                }
                const int row = rg + r;
                const int gs  = ((t >> 4) * 2 + batch) ^ (row & 7);
                *(bf16x8*)&z_s[row * 256 + gs * 8] = v;
            }
        }
    }
    __syncthreads();

    // ---- GEMM + packed-uint running argmin (no barriers, 2-deep B / 1-deep A pipeline)
    unsigned int best[16];
    #pragma unroll
    for (int i = 0; i < 16; i++) best[i] = 0xFFFFFFFFu;

    // A prefetch: dc=0 frags
    bf16x8 a0[4];
    {
        const int gs = q4 ^ (m16 & 7);
        #pragma unroll
        for (int i = 0; i < 4; i++)
            a0[i] = *(const bf16x8*)&z_s[(i * 16 + m16) * 256 + gs * 8];
    }

    #pragma unroll 1
    for (int it = 0; it < 8; it++) {
        const int kt  = (kt0 + (it << 7)) & 1023;
        const int ktn = (kt0 + (((it + 1) & 7) << 7)) & 1023;
        // per-chunk code norms (+1) and packed indices — hidden under MFMAs
        int   kcv[2];
        float sck[2];
        #pragma unroll
        for (int j = 0; j < 2; j++) {
            kcv[j] = kt + wc + j * 16 + m16;
            sck[j] = sc1[kcv[j]];
        }
        const __bf16* bc  = cbh + (size_t)(kt + wc + m16) * 256 + q4 * 8;
        const __bf16* bnx = cbh + (size_t)(ktn + wc + m16) * 256 + q4 * 8;

        f32x4 acc[4][2];
        #pragma unroll
        for (int i = 0; i < 4; i++)
            #pragma unroll
            for (int j = 0; j < 2; j++) acc[i][j] = (f32x4){0.f, 0.f, 0.f, 0.f};

        #pragma unroll
        for (int dcs = 0; dcs < 8; dcs++) {
            const int dc = dcs * 32;
            // B prefetch 2 iterations ahead (crosses into next kt at dcs=6,7)
            bf16x8 bn[2];
            const __bf16* bp = (dcs < 6) ? (bc + dc + 64) : (bnx + (dc - 192));
            bn[0] = *(const bf16x8*)bp;
            bn[1] = *(const bf16x8*)(bp + 4096);

            // A prefetch 1 iteration ahead (wraps to dc=0 at dcs=7 for next kt)
            bf16x8 an[4];
            {
                const int gs = ((((dc + 32) & 255) >> 3) + q4) ^ (m16 & 7);
                #pragma unroll
                for (int i = 0; i < 4; i++)
                    an[i] = *(const bf16x8*)&z_s[(i * 16 + m16) * 256 + gs * 8];
            }

            // MFMA burst on current a0 x bb0
            #pragma unroll
            for (int i = 0; i < 4; i++)
                #pragma unroll
                for (int j = 0; j < 2; j++)
                    acc[i][j] = __builtin_amdgcn_mfma_f32_16x16x32_bf16(a0[i], bb0[j], acc[i][j], 0, 0, 0);

            // rotate pipeline registers (SSA-renamed by full unroll; no real movs)
            #pragma unroll
            for (int i = 0; i < 4; i++) a0[i] = an[i];
            bb0[0] = bb1[0]; bb0[1] = bb1[1];
            bb1[0] = bn[0];  bb1[1] = bn[1];
        }

        // packed argmin: score = 1 + ||c||^2 - 2 z.c  > 0 always
        #pragma unroll
        for (int j = 0; j < 2; j++) {
            #pragma unroll
            for (int i = 0; i < 4; i++)
                #pragma unroll
                for (int r = 0; r < 4; r++) {
                    float v3 = fmaf(-2.f, acc[i][j][r], sck[j]);
                    unsigned int key = (__float_as_uint(v3) & 0xFFFFFC00u) | (unsigned int)kcv[j];
                    int pos = i * 4 + r;
                    best[pos] = min(best[pos], key);
                }
        }
    }

    // ---- intra-wave min across the 16 col-lanes
    #pragma unroll
    for (int pos = 0; pos < 16; pos++) {
        unsigned int k = best[pos];
        #pragma unroll
        for (int off = 1; off < 16; off <<= 1)
            k = min(k, (unsigned int)__shfl_xor((int)k, off, 64));
        best[pos] = k;
    }
    __syncthreads();              // all z_s reads done -> z_s becomes scratch

    // ---- cross-wave combine in recycled z_s
    // ks[0..256): key[wave][row] (each wave owns a distinct code quarter);
    // ks[256..320): chosen k
    unsigned int* ks = (unsigned int*)z_s;
    if (m16 == 0) {
        #pragma unroll
        for (int pos = 0; pos < 16; pos++) {
            int i = pos >> 2, r = pos & 3;
            int row = i * 16 + q4 * 4 + r;
            ks[w * 64 + row] = best[pos];
        }
    }
    __syncthreads();
    if (t < 64) {
        unsigned int key = min(min(ks[t], ks[64 + t]), min(ks[128 + t], ks[192 + t]));
        int kf = (int)(key & 1023u);
        ks[256 + t] = (unsigned int)kf;
        out[IDX_OFF + n0 + t] = (float)kf;
        lz += __uint_as_float(key & 0xFFFFFC00u) - 1.0f;   // best score (unshifted)
    }
    {
        float s = lz;
        #pragma unroll
        for (int off = 1; off < 64; off <<= 1) s += __shfl_xor(s, off, 64);
        if (lane == 0) red_s[w] = s;
    }
    __syncthreads();              // ks[256..320) and red_s visible
    if (t == 0)
        atomicAdd(out + LOSS_OFF, 1.25f * ((red_s[0] + red_s[1]) + (red_s[2] + red_s[3])));

    // ---- stage chosen codebook rows into z_s, then coalesced emit
    const int qrow = t >> 2;              // 0..63
    const int qoff = (t & 3) * 64;        // d offset 0/64/128/192
    const int myk  = (int)ks[256 + qrow];
    __syncthreads();              // everyone read their k; safe to overwrite z_s
    {
        const __bf16* qp = cbh + (size_t)myk * 256 + qoff;
        #pragma unroll
        for (int p = 0; p < 8; p++) {
            bf16x8 v = *(const bf16x8*)(qp + p * 8);
            int gs = ((qoff >> 3) + p) ^ (qrow & 7);
            *(bf16x8*)&z_s[qrow * 256 + gs * 8] = v;
        }
    }
    __syncthreads();
    {
        const int nl   = t & 63;
        const int dseg = t >> 6;
        float* op = out + (size_t)(b * 256 + dseg * 64) * 1024 + hw0 + nl;
        #pragma unroll
        for (int p = 0; p < 8; p++) {
            int gs = (dseg * 8 + p) ^ (nl & 7);
            bf16x8 v = *(const bf16x8*)&z_s[nl * 256 + gs * 8];
            #pragma unroll
            for (int j = 0; j < 8; j++)
                op[(size_t)(p * 8 + j) * 1024] = (float)v[j];
        }
    }
}

extern "C" void kernel_launch(void* const* d_in, const int* in_sizes, int n_in,
                              void* d_out, int out_size, void* d_ws, size_t ws_size,
                              hipStream_t stream) {
    const float* z  = (const float*)d_in[0];   // 16777216
    const float* cb = (const float*)d_in[1];   // 262144
    float* out = (float*)d_out;

    float*  sc1 = (float*)d_ws;                        // 1024 f  (1 + ||c||^2)
    __bf16* cbh = (__bf16*)((char*)d_ws + 8192);       // 512 KB bf16 codebook

    hipMemsetAsync(out + LOSS_OFF, 0, sizeof(float), stream);   // capture-safe
    vq_prep<<<64, 256, 0, stream>>>(cb, cbh, sc1);
    vq_mfma<<<1024, 256, 0, stream>>>(z, cbh, sc1, out);
}